// Round 16
// baseline (545.907 us; speedup 1.0000x reference)
//
#include <hip/hip_runtime.h>
#include <stdint.h>
#include <stddef.h>

typedef __bf16 bf16;
typedef __bf16 bf16x8 __attribute__((ext_vector_type(8)));
typedef __bf16 bf16x4 __attribute__((ext_vector_type(4)));
typedef float  f32x4  __attribute__((ext_vector_type(4)));

#define NB      4096        // batch
#define NF      4096        // features (= K = N for all GEMMs)
#define NCODES  (NB * NF / 64)   // 262144
#define NEMB    512
#define EDIM    64

// ---------------------------------------------------------------- helpers
__device__ __forceinline__ void gld_lds16(const void* g, void* l) {
  __builtin_amdgcn_global_load_lds(
      (const __attribute__((address_space(1))) void*)g,
      (__attribute__((address_space(3))) void*)l, 16, 0, 0);
}

__device__ __forceinline__ void cvt8(const float* in, bf16* out, int i) {
  const float4* p = (const float4*)(in + (size_t)i * 8);
  float4 a = p[0], b = p[1];
  bf16x8 o;
  o[0] = (bf16)a.x; o[1] = (bf16)a.y; o[2] = (bf16)a.z; o[3] = (bf16)a.w;
  o[4] = (bf16)b.x; o[5] = (bf16)b.y; o[6] = (bf16)b.z; o[7] = (bf16)b.w;
  *(bf16x8*)(out + (size_t)i * 8) = o;
}

// ---------------------------------------------------------------- prep: cvt(x) + cvt(W1) + cbprep + zero
__global__ void prep_k(const float* __restrict__ x,  bf16* __restrict__ xbf,
                       const float* __restrict__ w1, bf16* __restrict__ w1b,
                       const float* __restrict__ cb, bf16* __restrict__ cbbf,
                       float* __restrict__ cbnorm,
                       unsigned* __restrict__ hist, float* __restrict__ sse, int n8) {
  int b = blockIdx.x, tid = threadIdx.x;
  if (b < 2048) {
    for (int i = b * 256 + tid; i < n8; i += 2048 * 256) cvt8(x, xbf, i);
  } else if (b < 4096) {
    for (int i = (b - 2048) * 256 + tid; i < n8; i += 2048 * 256) cvt8(w1, w1b, i);
  } else {
    int r = (b - 4096) * 256 + tid;
    if (r < NEMB) {
      float s = 0.f;
      for (int d = 0; d < EDIM; ++d) {
        float v = cb[r * EDIM + d];
        s += v * v;
        cbbf[r * EDIM + d] = (bf16)v;
      }
      cbnorm[r] = s;
      hist[r] = 0;
      if (r == 0) sse[0] = 0.f;
    }
  }
}

// ---------------------------------------------------------------- GEMM 256x256, 8-phase/2-tile
// (R7 schedule, frozen; 16x16x32 MFMA). MODE: 0 = f32 out + fused finalize (block 0),
// 1 = bf16 out + relu, 2 = fused VQ. DOCVT: background-convert the NEXT gemm's weight;
// load after PH4's barrier, store after PH8's barrier (outside counted-vmcnt windows).
#define BAR()   __builtin_amdgcn_s_barrier()
#define LGKM(n) asm volatile("s_waitcnt lgkmcnt(" #n ")" ::: "memory")
#define VMC(n)  asm volatile("s_waitcnt vmcnt(" #n ")" ::: "memory")
#define PRIO(n) __builtin_amdgcn_s_setprio(n)

#define RD_A4(d0, d1, base, rb) do {                                          \
    d0[0] = *(const bf16x8*)((base) + (rb)*4096 + 0*1024 + boff0);            \
    d1[0] = *(const bf16x8*)((base) + (rb)*4096 + 0*1024 + boff1);            \
    d0[1] = *(const bf16x8*)((base) + (rb)*4096 + 1*1024 + boff0);            \
    d1[1] = *(const bf16x8*)((base) + (rb)*4096 + 1*1024 + boff1);            \
    d0[2] = *(const bf16x8*)((base) + (rb)*4096 + 2*1024 + boff0);            \
    d1[2] = *(const bf16x8*)((base) + (rb)*4096 + 2*1024 + boff1);            \
    d0[3] = *(const bf16x8*)((base) + (rb)*4096 + 3*1024 + boff0);            \
    d1[3] = *(const bf16x8*)((base) + (rb)*4096 + 3*1024 + boff1); } while (0)

#define RD_B2(d0, d1, base, j0) do {                                          \
    d0[j0]   = *(const bf16x8*)((base) + (j0)*1024     + boff0);              \
    d1[j0]   = *(const bf16x8*)((base) + (j0)*1024     + boff1);              \
    d0[j0+1] = *(const bf16x8*)((base) + ((j0)+1)*1024 + boff0);              \
    d1[j0+1] = *(const bf16x8*)((base) + ((j0)+1)*1024 + boff1); } while (0)

#define MQ(ib, jb, A0a, A1a) do {                                             \
    _Pragma("unroll")                                                         \
    for (int fr = 0; fr < 4; ++fr) {                                          \
      _Pragma("unroll")                                                       \
      for (int jc = 0; jc < 2; ++jc) {                                        \
        acc[(ib)+fr][(jb)+jc] = __builtin_amdgcn_mfma_f32_16x16x32_bf16(      \
            A0a[fr], b0[(jb)+jc], acc[(ib)+fr][(jb)+jc], 0, 0, 0);            \
        acc[(ib)+fr][(jb)+jc] = __builtin_amdgcn_mfma_f32_16x16x32_bf16(      \
            A1a[fr], b1[(jb)+jc], acc[(ib)+fr][(jb)+jc], 0, 0, 0);            \
      } } } while (0)

template<int MODE, int DOCVT>
__global__ __launch_bounds__(512, 2)
void gemm256(const bf16* __restrict__ A, const bf16* __restrict__ W,
             const float* __restrict__ bias,
             float* __restrict__ outF, bf16* __restrict__ outB,
             const bf16* __restrict__ cbbf, const float* __restrict__ cbnorm,
             unsigned int* __restrict__ hist, float* __restrict__ sse_out,
             const float* __restrict__ cvsrc, bf16* __restrict__ cvdst) {
  constexpr int K = 4096, N = 4096, NT = 64;
  __shared__ bf16 SM[65536];          // 128 KB
  __shared__ unsigned lhist[NEMB];    // VQ epilogue only
  __shared__ float swse[8];

  const int tid = threadIdx.x;
  const int wave = tid >> 6, lane = tid & 63;
  const int l15 = lane & 15, lg = lane >> 4;
  const int wm = wave >> 2, wn = wave & 3;
  const int rb0 = (wn & 1) * 64;

  // XCD-bijective swizzle (256 blocks, 256 % 8 == 0)
  const int bid = blockIdx.x;
  const int lb  = (bid & 7) * 32 + (bid >> 3);
  const int bx = lb & 15, by = lb >> 4;
  const int brow = by * 256, bcol = bx * 256;

  // hoisted per-lane ds_read bases
  const int boff0 = l15 * 64 + ((lg ^ (l15 & 7)) * 8);
  const int boff1 = boff0 ^ 32;

  // staging: thread covers units u1,u2 of each 1024-unit half-tile
  const int u1 = tid,       r1 = u1 >> 3, ss1 = (u1 & 7) ^ (r1 & 7);
  const int u2 = tid + 512, r2 = u2 >> 3, ss2 = (u2 & 7) ^ (r2 & 7);
  const size_t tofs1 = (size_t)r1 * K + ss1 * 8;
  const size_t tofs2 = (size_t)r2 * K + ss2 * 8;
  const bf16* gW0 = W + (size_t)bcol * K;
  const bf16* gW1 = W + (size_t)(bcol + 128) * K;
  const bf16* gA0 = A + (size_t)brow * K;
  const bf16* gA1 = A + (size_t)(brow + 128) * K;

  // background-convert slice: block covers 65536 floats, thread 4/iter x 32 iters
  const size_t cvofs = (size_t)bid * 65536 + tid * 4;

#define STAGE(gptr, k_, ldsh) do {                                        \
    gld_lds16((gptr) + tofs1 + (size_t)(k_) * 64, (ldsh) + u1 * 8);       \
    gld_lds16((gptr) + tofs2 + (size_t)(k_) * 64, (ldsh) + u2 * 8); } while (0)

  bf16* as00 = SM;         bf16* as01 = SM + 8192;
  bf16* as10 = SM + 16384; bf16* as11 = SM + 24576;
  bf16* bs00 = SM + 32768; bf16* bs01 = SM + 40960;
  bf16* bs10 = SM + 49152; bf16* bs11 = SM + 57344;

  const bf16* Ae = SM + wm * 8192;
  const bf16* Ao = SM + 16384 + wm * 8192;
  const bf16* Be = SM + 32768 + (wn >> 1) * 8192 + rb0 * 64;
  const bf16* Bo = SM + 49152 + (wn >> 1) * 8192 + rb0 * 64;

  f32x4 acc[8][4];
#pragma unroll
  for (int i = 0; i < 8; ++i)
#pragma unroll
    for (int j = 0; j < 4; ++j)
      acc[i][j] = f32x4{0.f, 0.f, 0.f, 0.f};

  bf16x8 aE0[4], aE1[4];
  bf16x8 aF0[4], aF1[4];
  bf16x8 b0[4],  b1[4];

  // prologue: tile0 complete + tile1 {A0,A1,B0}; vmcnt(6) -> tile0 certified
  STAGE(gA0, 0, as00); STAGE(gA1, 0, as01);
  STAGE(gW0, 0, bs00); STAGE(gW1, 0, bs01);
  STAGE(gA0, 1, as10); STAGE(gA1, 1, as11);
  STAGE(gW0, 1, bs10);
  VMC(6);
  BAR();

  for (int kt = 0; kt < NT; kt += 2) {
    const int kE = (kt + 2) & (NT - 1);
    const int kO = (kt + 3) & (NT - 1);
    float4 cf;

    // PH1
    RD_A4(aE0, aE1, Ae, 0);
    RD_B2(b0, b1, Be, 0);
    STAGE(gW1, kt + 1, bs11);
    LGKM(8); BAR(); LGKM(0);
    PRIO(1); MQ(0, 0, aE0, aE1); PRIO(0); BAR();

    // PH2
    RD_A4(aF0, aF1, Ae, 1);
    STAGE(gA0, kE, as00);
    BAR(); LGKM(0);
    PRIO(1); MQ(4, 0, aF0, aF1); PRIO(0); BAR();

    // PH3
    RD_B2(b0, b1, Be, 2);
    STAGE(gA1, kE, as01);
    BAR(); LGKM(0);
    PRIO(1); MQ(0, 2, aE0, aE1); PRIO(0); BAR();

    // PH4
    STAGE(gW0, kE, bs00);
    BAR();
    PRIO(1); MQ(4, 2, aF0, aF1); PRIO(0);
    VMC(6); BAR();
    if (DOCVT) cf = *(const float4*)(cvsrc + cvofs + (size_t)(kt >> 1) * 2048);

    // PH5
    RD_A4(aE0, aE1, Ao, 0);
    RD_B2(b0, b1, Bo, 0);
    STAGE(gW1, kE, bs01);
    LGKM(8); BAR(); LGKM(0);
    PRIO(1); MQ(0, 0, aE0, aE1); PRIO(0); BAR();

    // PH6
    RD_A4(aF0, aF1, Ao, 1);
    STAGE(gA0, kO, as10);
    BAR(); LGKM(0);
    PRIO(1); MQ(4, 0, aF0, aF1); PRIO(0); BAR();

    // PH7
    RD_B2(b0, b1, Bo, 2);
    STAGE(gA1, kO, as11);
    BAR(); LGKM(0);
    PRIO(1); MQ(0, 2, aE0, aE1); PRIO(0); BAR();

    // PH8
    STAGE(gW0, kO, bs10);
    BAR();
    PRIO(1); MQ(4, 2, aF0, aF1); PRIO(0);
    VMC(6); BAR();
    if (DOCVT) {
      bf16x4 c4;
      c4[0] = (bf16)cf.x; c4[1] = (bf16)cf.y; c4[2] = (bf16)cf.z; c4[3] = (bf16)cf.w;
      *(bf16x4*)(cvdst + cvofs + (size_t)(kt >> 1) * 2048) = c4;
    }
  }
#undef STAGE

  if (MODE == 2) {
    // -------- fused VQ epilogue (single-pass; bf16 codebook for qv/SSE) --------
    __syncthreads();                 // all LDS reads of the K-loop done
    lhist[tid] = 0;
    // write (acc + bias) as bf16 codes into wave-private swizzled scratch
    bf16* scr = SM + wave * 8192;    // 128 rows x 64 dims, main-loop swizzle geometry
#pragma unroll
    for (int j = 0; j < 4; ++j) {
      float bv = bias[bcol + wn * 64 + j * 16 + l15];
#pragma unroll
      for (int i = 0; i < 8; ++i) {
#pragma unroll
        for (int rr = 0; rr < 4; ++rr) {
          int r = i * 16 + lg * 4 + rr;
          int d = j * 16 + l15;
          scr[r * 64 + (((d >> 3) ^ (r & 7)) << 3) + (d & 7)] =
              (bf16)(acc[i][j][rr] + bv);
        }
      }
    }
    __syncthreads();

    // load all 8 code-groups as A-frags
    bf16x8 ca0[8], ca1[8];
#pragma unroll
    for (int g = 0; g < 8; ++g) {
      ca0[g] = *(const bf16x8*)(scr + g * 1024 + boff0);
      ca1[g] = *(const bf16x8*)(scr + g * 1024 + boff1);
    }
    float best[8][4];
    int   bidx[8][4];
#pragma unroll
    for (int g = 0; g < 8; ++g)
#pragma unroll
      for (int r = 0; r < 4; ++r) { best[g][r] = 1e30f; bidx[g][r] = 0; }

#pragma unroll 4
    for (int ct = 0; ct < 32; ++ct) {
      const bf16* bp = cbbf + (ct * 16 + l15) * 64 + lg * 8;
      bf16x8 q0 = *(const bf16x8*)bp;
      bf16x8 q1 = *(const bf16x8*)(bp + 32);
      float cn = cbnorm[ct * 16 + l15];
      int c = ct * 16 + l15;
#pragma unroll
      for (int g = 0; g < 8; ++g) {
        f32x4 da = f32x4{0.f, 0.f, 0.f, 0.f};
        da = __builtin_amdgcn_mfma_f32_16x16x32_bf16(ca0[g], q0, da, 0, 0, 0);
        da = __builtin_amdgcn_mfma_f32_16x16x32_bf16(ca1[g], q1, da, 0, 0, 0);
#pragma unroll
        for (int r = 0; r < 4; ++r) {
          float s = fmaf(-2.0f, da[r], cn);
          if (s < best[g][r]) { best[g][r] = s; bidx[g][r] = c; }
        }
      }
    }

    float sse = 0.f;
    const int gcol = bcol + wn * 64;
#pragma unroll
    for (int g = 0; g < 8; ++g) {
#pragma unroll
      for (int r = 0; r < 4; ++r) {
        uint32_t bits = __float_as_uint(best[g][r]);
        uint32_t u = bits ^ ((uint32_t)((int32_t)bits >> 31) | 0x80000000u);
        uint32_t key = (u & 0xFFFFFE00u) | (uint32_t)bidx[g][r];
#pragma unroll
        for (int m = 1; m < 16; m <<= 1) {
          uint32_t o = __shfl_xor(key, m);
          key = (o < key) ? o : key;
        }
        int idx = (int)(key & 511u);
        int rowl = g * 16 + lg * 4 + r;
        bf16x4 cv = *(const bf16x4*)(scr + rowl * 64 +
                        (((l15 >> 1) ^ (rowl & 7)) << 3) + (l15 & 1) * 4);
        // quantized entry direct from bf16 codebook: identical bits to (bf16)cb
        bf16x4 ev = *(const bf16x4*)(cbbf + (size_t)idx * EDIM + l15 * 4);
        float d0 = (float)ev[0] - (float)cv[0], d1 = (float)ev[1] - (float)cv[1];
        float d2 = (float)ev[2] - (float)cv[2], d3 = (float)ev[3] - (float)cv[3];
        sse += d0 * d0 + d1 * d1 + d2 * d2 + d3 * d3;
        *(bf16x4*)(outB + (size_t)(brow + wm * 128 + rowl) * N + gcol + l15 * 4) = ev;
        if (l15 == 0) atomicAdd(&lhist[idx], 1u);
      }
    }
#pragma unroll
    for (int m = 1; m < 64; m <<= 1) sse += __shfl_xor(sse, m);
    if (lane == 0) swse[wave] = sse;
    __syncthreads();
    { unsigned v = lhist[tid]; if (v) atomicAdd(hist + tid, v); }
    if (tid == 0) {
      float s = 0.f;
#pragma unroll
      for (int w = 0; w < 8; ++w) s += swse[w];
      atomicAdd(sse_out, s);
    }
    return;
  }

  // -------- dense epilogue (MODE 0/1) --------
#pragma unroll
  for (int j = 0; j < 4; ++j) {
    int col = bcol + wn * 64 + j * 16 + l15;
    float bv = bias[col];
#pragma unroll
    for (int i = 0; i < 8; ++i) {
#pragma unroll
      for (int rr = 0; rr < 4; ++rr) {
        int row = brow + wm * 128 + i * 16 + lg * 4 + rr;
        float v = acc[i][j][rr] + bv;
        if (MODE == 1) v = fmaxf(v, 0.f);
        size_t o = (size_t)row * N + col;
        if (MODE == 0) outF[o] = v;
        else           outB[o] = (bf16)v;
      }
    }
  }

  // -------- fused finalize (MODE 0, block 0): vq_loss + perplexity --------
  // hist/sse were completed by the MODE==2 gemm, which finished before this
  // kernel launched (stream order); device-scope atomics are visible here.
  if (MODE == 0 && bid == 0) {
    float p = (float)hist[tid] * (1.0f / (float)NCODES);
    float v = p * logf(p + 1e-10f);
#pragma unroll
    for (int m = 1; m < 64; m <<= 1) v += __shfl_xor(v, m);
    if (lane == 0) swse[wave] = v;
    __syncthreads();
    if (tid == 0) {
      float s = 0.f;
#pragma unroll
      for (int w = 0; w < 8; ++w) s += swse[w];
      outF[(size_t)NB * NF]     = 1.25f * sse_out[0] * (1.0f / ((float)NCODES * (float)EDIM));
      outF[(size_t)NB * NF + 1] = expf(-s);
    }
  }
}

// ---------------------------------------------------------------- launch
extern "C" void kernel_launch(void* const* d_in, const int* in_sizes, int n_in,
                              void* d_out, int out_size, void* d_ws, size_t ws_size,
                              hipStream_t stream) {
  const float* x  = (const float*)d_in[0];
  const float* W1 = (const float*)d_in[1];
  const float* b1 = (const float*)d_in[2];
  const float* W2 = (const float*)d_in[3];
  const float* b2 = (const float*)d_in[4];
  const float* W3 = (const float*)d_in[5];
  const float* b3 = (const float*)d_in[6];
  const float* W4 = (const float*)d_in[7];
  const float* b4 = (const float*)d_in[8];
  const float* cb = (const float*)d_in[9];
  float* out = (float*)d_out;

  char* ws = (char*)d_ws;
  float*    sse    = (float*)(ws + 0);
  unsigned* hist   = (unsigned*)(ws + 1024);
  float*    cbnorm = (float*)(ws + 4096);
  bf16*     cbbf   = (bf16*)(ws + 8192);
  size_t off = 131072;
  const size_t MSZ = (size_t)NB * NF * 2;          // 33.5 MB
  bf16* xbf = (bf16*)(ws + off);  off += MSZ;
  bf16* w1b = (bf16*)(ws + off);  off += MSZ;
  bf16* w2b = (bf16*)(ws + off);  off += MSZ;
  bf16* w3b = (bf16*)(ws + off);  off += MSZ;
  bf16* w4b = (bf16*)(ws + off);  off += MSZ;
  bf16* hbf = (bf16*)(ws + off);  off += MSZ;
  bf16* qbf  = xbf;   // alias: x dead after GEMM1
  bf16* h2bf = hbf;   // alias: h dead after GEMM2(VQ)

  const int n8 = NB * NF / 8;
  prep_k<<<dim3(4098), dim3(256), 0, stream>>>(x, xbf, W1, w1b, cb, cbbf, cbnorm,
                                               hist, sse, n8);

  dim3 ggrid(256), gblock(512);
  // h = relu(x @ W1^T + b1) -> bf16; background-converts W2
  gemm256<1, 1><<<ggrid, gblock, 0, stream>>>(xbf, w1b, b1, nullptr, hbf,
                                              nullptr, nullptr, nullptr, nullptr,
                                              W2, w2b);
  // latent = h @ W2^T + b2, fused VQ -> qbf + hist + sse; background-converts W3
  gemm256<2, 1><<<ggrid, gblock, 0, stream>>>(hbf, w2b, b2, nullptr, qbf,
                                              cbbf, cbnorm, hist, sse,
                                              W3, w3b);
  // h2 = relu(q @ W3^T + b3) -> bf16; background-converts W4
  gemm256<1, 1><<<ggrid, gblock, 0, stream>>>(qbf, w3b, b3, nullptr, h2bf,
                                              nullptr, nullptr, nullptr, nullptr,
                                              W4, w4b);
  // recons = h2 @ W4^T + b4 -> f32 (d_out); block 0 also writes vq_loss + perplexity
  gemm256<0, 0><<<ggrid, gblock, 0, stream>>>(h2bf, w4b, b4, out, nullptr,
                                              nullptr, nullptr, hist, sse,
                                              nullptr, nullptr);
}

// Round 17
// 540.091 us; speedup vs baseline: 1.0108x; 1.0108x over previous
//
#include <hip/hip_runtime.h>
#include <stdint.h>
#include <stddef.h>

typedef __bf16 bf16;
typedef __bf16 bf16x8 __attribute__((ext_vector_type(8)));
typedef __bf16 bf16x4 __attribute__((ext_vector_type(4)));
typedef float  f32x4  __attribute__((ext_vector_type(4)));

#define NB      4096        // batch
#define NF      4096        // features (= K = N for all GEMMs)
#define NCODES  (NB * NF / 64)   // 262144
#define NEMB    512
#define EDIM    64

// ---------------------------------------------------------------- helpers
__device__ __forceinline__ void gld_lds16(const void* g, void* l) {
  __builtin_amdgcn_global_load_lds(
      (const __attribute__((address_space(1))) void*)g,
      (__attribute__((address_space(3))) void*)l, 16, 0, 0);
}

__device__ __forceinline__ void cvt8(const float* in, bf16* out, int i) {
  const float4* p = (const float4*)(in + (size_t)i * 8);
  float4 a = p[0], b = p[1];
  bf16x8 o;
  o[0] = (bf16)a.x; o[1] = (bf16)a.y; o[2] = (bf16)a.z; o[3] = (bf16)a.w;
  o[4] = (bf16)b.x; o[5] = (bf16)b.y; o[6] = (bf16)b.z; o[7] = (bf16)b.w;
  *(bf16x8*)(out + (size_t)i * 8) = o;
}

// ---------------------------------------------------------------- prep: cvt(x) + cvt(W1) + cbprep + zero
__global__ void prep_k(const float* __restrict__ x,  bf16* __restrict__ xbf,
                       const float* __restrict__ w1, bf16* __restrict__ w1b,
                       const float* __restrict__ cb, bf16* __restrict__ cbbf,
                       float* __restrict__ cbnorm,
                       unsigned* __restrict__ hist, float* __restrict__ sse, int n8) {
  int b = blockIdx.x, tid = threadIdx.x;
  if (b < 2048) {
    for (int i = b * 256 + tid; i < n8; i += 2048 * 256) cvt8(x, xbf, i);
  } else if (b < 4096) {
    for (int i = (b - 2048) * 256 + tid; i < n8; i += 2048 * 256) cvt8(w1, w1b, i);
  } else {
    int r = (b - 4096) * 256 + tid;
    if (r < NEMB) {
      float s = 0.f;
      for (int d = 0; d < EDIM; ++d) {
        float v = cb[r * EDIM + d];
        s += v * v;
        cbbf[r * EDIM + d] = (bf16)v;
      }
      cbnorm[r] = s;
      hist[r] = 0;
      if (r == 0) sse[0] = 0.f;
    }
  }
}

// ---------------------------------------------------------------- GEMM 256x256, 8-phase/2-tile
// (R7 schedule, frozen; 16x16x32 MFMA). MODE: 0 = f32 out, 1 = bf16 out + relu,
// 2 = fused VQ. DOCVT: background-convert the NEXT gemm's weight using idle HBM BW;
// load after PH4's barrier, store after PH8's barrier (outside counted-vmcnt windows).
#define BAR()   __builtin_amdgcn_s_barrier()
#define LGKM(n) asm volatile("s_waitcnt lgkmcnt(" #n ")" ::: "memory")
#define VMC(n)  asm volatile("s_waitcnt vmcnt(" #n ")" ::: "memory")
#define PRIO(n) __builtin_amdgcn_s_setprio(n)

#define RD_A4(d0, d1, base, rb) do {                                          \
    d0[0] = *(const bf16x8*)((base) + (rb)*4096 + 0*1024 + boff0);            \
    d1[0] = *(const bf16x8*)((base) + (rb)*4096 + 0*1024 + boff1);            \
    d0[1] = *(const bf16x8*)((base) + (rb)*4096 + 1*1024 + boff0);            \
    d1[1] = *(const bf16x8*)((base) + (rb)*4096 + 1*1024 + boff1);            \
    d0[2] = *(const bf16x8*)((base) + (rb)*4096 + 2*1024 + boff0);            \
    d1[2] = *(const bf16x8*)((base) + (rb)*4096 + 2*1024 + boff1);            \
    d0[3] = *(const bf16x8*)((base) + (rb)*4096 + 3*1024 + boff0);            \
    d1[3] = *(const bf16x8*)((base) + (rb)*4096 + 3*1024 + boff1); } while (0)

#define RD_B2(d0, d1, base, j0) do {                                          \
    d0[j0]   = *(const bf16x8*)((base) + (j0)*1024     + boff0);              \
    d1[j0]   = *(const bf16x8*)((base) + (j0)*1024     + boff1);              \
    d0[j0+1] = *(const bf16x8*)((base) + ((j0)+1)*1024 + boff0);              \
    d1[j0+1] = *(const bf16x8*)((base) + ((j0)+1)*1024 + boff1); } while (0)

#define MQ(ib, jb, A0a, A1a) do {                                             \
    _Pragma("unroll")                                                         \
    for (int fr = 0; fr < 4; ++fr) {                                          \
      _Pragma("unroll")                                                       \
      for (int jc = 0; jc < 2; ++jc) {                                        \
        acc[(ib)+fr][(jb)+jc] = __builtin_amdgcn_mfma_f32_16x16x32_bf16(      \
            A0a[fr], b0[(jb)+jc], acc[(ib)+fr][(jb)+jc], 0, 0, 0);            \
        acc[(ib)+fr][(jb)+jc] = __builtin_amdgcn_mfma_f32_16x16x32_bf16(      \
            A1a[fr], b1[(jb)+jc], acc[(ib)+fr][(jb)+jc], 0, 0, 0);            \
      } } } while (0)

template<int MODE, int DOCVT>
__global__ __launch_bounds__(512, 2)
void gemm256(const bf16* __restrict__ A, const bf16* __restrict__ W,
             const float* __restrict__ bias,
             float* __restrict__ outF, bf16* __restrict__ outB,
             const bf16* __restrict__ cbbf, const float* __restrict__ cbnorm,
             unsigned int* __restrict__ hist, float* __restrict__ sse_out,
             const float* __restrict__ cvsrc, bf16* __restrict__ cvdst) {
  constexpr int K = 4096, N = 4096, NT = 64;
  __shared__ bf16 SM[65536];          // 128 KB
  __shared__ unsigned lhist[NEMB];    // VQ epilogue only
  __shared__ float swse[8];

  const int tid = threadIdx.x;
  const int wave = tid >> 6, lane = tid & 63;
  const int l15 = lane & 15, lg = lane >> 4;
  const int wm = wave >> 2, wn = wave & 3;
  const int rb0 = (wn & 1) * 64;

  // XCD-bijective swizzle (256 blocks, 256 % 8 == 0)
  const int bid = blockIdx.x;
  const int lb  = (bid & 7) * 32 + (bid >> 3);
  const int bx = lb & 15, by = lb >> 4;
  const int brow = by * 256, bcol = bx * 256;

  // hoisted per-lane ds_read bases
  const int boff0 = l15 * 64 + ((lg ^ (l15 & 7)) * 8);
  const int boff1 = boff0 ^ 32;

  // staging: thread covers units u1,u2 of each 1024-unit half-tile
  const int u1 = tid,       r1 = u1 >> 3, ss1 = (u1 & 7) ^ (r1 & 7);
  const int u2 = tid + 512, r2 = u2 >> 3, ss2 = (u2 & 7) ^ (r2 & 7);
  const size_t tofs1 = (size_t)r1 * K + ss1 * 8;
  const size_t tofs2 = (size_t)r2 * K + ss2 * 8;
  const bf16* gW0 = W + (size_t)bcol * K;
  const bf16* gW1 = W + (size_t)(bcol + 128) * K;
  const bf16* gA0 = A + (size_t)brow * K;
  const bf16* gA1 = A + (size_t)(brow + 128) * K;

  // background-convert slice: block covers 65536 floats, thread 4/iter x 32 iters
  const size_t cvofs = (size_t)bid * 65536 + tid * 4;

#define STAGE(gptr, k_, ldsh) do {                                        \
    gld_lds16((gptr) + tofs1 + (size_t)(k_) * 64, (ldsh) + u1 * 8);       \
    gld_lds16((gptr) + tofs2 + (size_t)(k_) * 64, (ldsh) + u2 * 8); } while (0)

  bf16* as00 = SM;         bf16* as01 = SM + 8192;
  bf16* as10 = SM + 16384; bf16* as11 = SM + 24576;
  bf16* bs00 = SM + 32768; bf16* bs01 = SM + 40960;
  bf16* bs10 = SM + 49152; bf16* bs11 = SM + 57344;

  const bf16* Ae = SM + wm * 8192;
  const bf16* Ao = SM + 16384 + wm * 8192;
  const bf16* Be = SM + 32768 + (wn >> 1) * 8192 + rb0 * 64;
  const bf16* Bo = SM + 49152 + (wn >> 1) * 8192 + rb0 * 64;

  f32x4 acc[8][4];
#pragma unroll
  for (int i = 0; i < 8; ++i)
#pragma unroll
    for (int j = 0; j < 4; ++j)
      acc[i][j] = f32x4{0.f, 0.f, 0.f, 0.f};

  bf16x8 aE0[4], aE1[4];
  bf16x8 aF0[4], aF1[4];
  bf16x8 b0[4],  b1[4];

  // prologue: tile0 complete + tile1 {A0,A1,B0}; vmcnt(6) -> tile0 certified
  STAGE(gA0, 0, as00); STAGE(gA1, 0, as01);
  STAGE(gW0, 0, bs00); STAGE(gW1, 0, bs01);
  STAGE(gA0, 1, as10); STAGE(gA1, 1, as11);
  STAGE(gW0, 1, bs10);
  VMC(6);
  BAR();

  for (int kt = 0; kt < NT; kt += 2) {
    const int kE = (kt + 2) & (NT - 1);
    const int kO = (kt + 3) & (NT - 1);
    float4 cf;

    // PH1
    RD_A4(aE0, aE1, Ae, 0);
    RD_B2(b0, b1, Be, 0);
    STAGE(gW1, kt + 1, bs11);
    LGKM(8); BAR(); LGKM(0);
    PRIO(1); MQ(0, 0, aE0, aE1); PRIO(0); BAR();

    // PH2
    RD_A4(aF0, aF1, Ae, 1);
    STAGE(gA0, kE, as00);
    BAR(); LGKM(0);
    PRIO(1); MQ(4, 0, aF0, aF1); PRIO(0); BAR();

    // PH3
    RD_B2(b0, b1, Be, 2);
    STAGE(gA1, kE, as01);
    BAR(); LGKM(0);
    PRIO(1); MQ(0, 2, aE0, aE1); PRIO(0); BAR();

    // PH4
    STAGE(gW0, kE, bs00);
    BAR();
    PRIO(1); MQ(4, 2, aF0, aF1); PRIO(0);
    VMC(6); BAR();
    if (DOCVT) cf = *(const float4*)(cvsrc + cvofs + (size_t)(kt >> 1) * 2048);

    // PH5
    RD_A4(aE0, aE1, Ao, 0);
    RD_B2(b0, b1, Bo, 0);
    STAGE(gW1, kE, bs01);
    LGKM(8); BAR(); LGKM(0);
    PRIO(1); MQ(0, 0, aE0, aE1); PRIO(0); BAR();

    // PH6
    RD_A4(aF0, aF1, Ao, 1);
    STAGE(gA0, kO, as10);
    BAR(); LGKM(0);
    PRIO(1); MQ(4, 0, aF0, aF1); PRIO(0); BAR();

    // PH7
    RD_B2(b0, b1, Bo, 2);
    STAGE(gA1, kO, as11);
    BAR(); LGKM(0);
    PRIO(1); MQ(0, 2, aE0, aE1); PRIO(0); BAR();

    // PH8
    STAGE(gW0, kO, bs10);
    BAR();
    PRIO(1); MQ(4, 2, aF0, aF1); PRIO(0);
    VMC(6); BAR();
    if (DOCVT) {
      bf16x4 c4;
      c4[0] = (bf16)cf.x; c4[1] = (bf16)cf.y; c4[2] = (bf16)cf.z; c4[3] = (bf16)cf.w;
      *(bf16x4*)(cvdst + cvofs + (size_t)(kt >> 1) * 2048) = c4;
    }
  }
#undef STAGE

  if (MODE == 2) {
    // -------- fused VQ epilogue (single-pass; bf16 codebook for qv/SSE) --------
    __syncthreads();                 // all LDS reads of the K-loop done
    lhist[tid] = 0;
    // write (acc + bias) as bf16 codes into wave-private swizzled scratch
    bf16* scr = SM + wave * 8192;    // 128 rows x 64 dims, main-loop swizzle geometry
#pragma unroll
    for (int j = 0; j < 4; ++j) {
      float bv = bias[bcol + wn * 64 + j * 16 + l15];
#pragma unroll
      for (int i = 0; i < 8; ++i) {
#pragma unroll
        for (int rr = 0; rr < 4; ++rr) {
          int r = i * 16 + lg * 4 + rr;
          int d = j * 16 + l15;
          scr[r * 64 + (((d >> 3) ^ (r & 7)) << 3) + (d & 7)] =
              (bf16)(acc[i][j][rr] + bv);
        }
      }
    }
    __syncthreads();

    // load all 8 code-groups as A-frags
    bf16x8 ca0[8], ca1[8];
#pragma unroll
    for (int g = 0; g < 8; ++g) {
      ca0[g] = *(const bf16x8*)(scr + g * 1024 + boff0);
      ca1[g] = *(const bf16x8*)(scr + g * 1024 + boff1);
    }
    float best[8][4];
    int   bidx[8][4];
#pragma unroll
    for (int g = 0; g < 8; ++g)
#pragma unroll
      for (int r = 0; r < 4; ++r) { best[g][r] = 1e30f; bidx[g][r] = 0; }

#pragma unroll 4
    for (int ct = 0; ct < 32; ++ct) {
      const bf16* bp = cbbf + (ct * 16 + l15) * 64 + lg * 8;
      bf16x8 q0 = *(const bf16x8*)bp;
      bf16x8 q1 = *(const bf16x8*)(bp + 32);
      float cn = cbnorm[ct * 16 + l15];
      int c = ct * 16 + l15;
#pragma unroll
      for (int g = 0; g < 8; ++g) {
        f32x4 da = f32x4{0.f, 0.f, 0.f, 0.f};
        da = __builtin_amdgcn_mfma_f32_16x16x32_bf16(ca0[g], q0, da, 0, 0, 0);
        da = __builtin_amdgcn_mfma_f32_16x16x32_bf16(ca1[g], q1, da, 0, 0, 0);
#pragma unroll
        for (int r = 0; r < 4; ++r) {
          float s = fmaf(-2.0f, da[r], cn);
          if (s < best[g][r]) { best[g][r] = s; bidx[g][r] = c; }
        }
      }
    }

    float sse = 0.f;
    const int gcol = bcol + wn * 64;
#pragma unroll
    for (int g = 0; g < 8; ++g) {
#pragma unroll
      for (int r = 0; r < 4; ++r) {
        uint32_t bits = __float_as_uint(best[g][r]);
        uint32_t u = bits ^ ((uint32_t)((int32_t)bits >> 31) | 0x80000000u);
        uint32_t key = (u & 0xFFFFFE00u) | (uint32_t)bidx[g][r];
#pragma unroll
        for (int m = 1; m < 16; m <<= 1) {
          uint32_t o = __shfl_xor(key, m);
          key = (o < key) ? o : key;
        }
        int idx = (int)(key & 511u);
        int rowl = g * 16 + lg * 4 + r;
        bf16x4 cv = *(const bf16x4*)(scr + rowl * 64 +
                        (((l15 >> 1) ^ (rowl & 7)) << 3) + (l15 & 1) * 4);
        // quantized entry direct from bf16 codebook: identical bits to (bf16)cb
        bf16x4 ev = *(const bf16x4*)(cbbf + (size_t)idx * EDIM + l15 * 4);
        float d0 = (float)ev[0] - (float)cv[0], d1 = (float)ev[1] - (float)cv[1];
        float d2 = (float)ev[2] - (float)cv[2], d3 = (float)ev[3] - (float)cv[3];
        sse += d0 * d0 + d1 * d1 + d2 * d2 + d3 * d3;
        *(bf16x4*)(outB + (size_t)(brow + wm * 128 + rowl) * N + gcol + l15 * 4) = ev;
        if (l15 == 0) atomicAdd(&lhist[idx], 1u);
      }
    }
#pragma unroll
    for (int m = 1; m < 64; m <<= 1) sse += __shfl_xor(sse, m);
    if (lane == 0) swse[wave] = sse;
    __syncthreads();
    { unsigned v = lhist[tid]; if (v) atomicAdd(hist + tid, v); }
    if (tid == 0) {
      float s = 0.f;
#pragma unroll
      for (int w = 0; w < 8; ++w) s += swse[w];
      atomicAdd(sse_out, s);
    }
    return;
  }

  // -------- dense epilogue (MODE 0/1) --------
#pragma unroll
  for (int j = 0; j < 4; ++j) {
    int col = bcol + wn * 64 + j * 16 + l15;
    float bv = bias[col];
#pragma unroll
    for (int i = 0; i < 8; ++i) {
#pragma unroll
      for (int rr = 0; rr < 4; ++rr) {
        int row = brow + wm * 128 + i * 16 + lg * 4 + rr;
        float v = acc[i][j][rr] + bv;
        if (MODE == 1) v = fmaxf(v, 0.f);
        size_t o = (size_t)row * N + col;
        if (MODE == 0) outF[o] = v;
        else           outB[o] = (bf16)v;
      }
    }
  }
}

// ---------------------------------------------------------------- finalize: vq_loss + perplexity
__global__ void finalize_k(const unsigned* __restrict__ hist, const float* __restrict__ sse,
                           float* __restrict__ out_tail) {
  __shared__ float red[512];
  int t = threadIdx.x;
  float p = (float)hist[t] * (1.0f / (float)NCODES);
  red[t] = p * logf(p + 1e-10f);
  __syncthreads();
  for (int s = 256; s > 0; s >>= 1) {
    if (t < s) red[t] += red[t + s];
    __syncthreads();
  }
  if (t == 0) {
    out_tail[0] = 1.25f * sse[0] * (1.0f / ((float)NCODES * (float)EDIM));
    out_tail[1] = expf(-red[0]);
  }
}

// ---------------------------------------------------------------- launch
extern "C" void kernel_launch(void* const* d_in, const int* in_sizes, int n_in,
                              void* d_out, int out_size, void* d_ws, size_t ws_size,
                              hipStream_t stream) {
  const float* x  = (const float*)d_in[0];
  const float* W1 = (const float*)d_in[1];
  const float* b1 = (const float*)d_in[2];
  const float* W2 = (const float*)d_in[3];
  const float* b2 = (const float*)d_in[4];
  const float* W3 = (const float*)d_in[5];
  const float* b3 = (const float*)d_in[6];
  const float* W4 = (const float*)d_in[7];
  const float* b4 = (const float*)d_in[8];
  const float* cb = (const float*)d_in[9];
  float* out = (float*)d_out;

  char* ws = (char*)d_ws;
  float*    sse    = (float*)(ws + 0);
  unsigned* hist   = (unsigned*)(ws + 1024);
  float*    cbnorm = (float*)(ws + 4096);
  bf16*     cbbf   = (bf16*)(ws + 8192);
  size_t off = 131072;
  const size_t MSZ = (size_t)NB * NF * 2;          // 33.5 MB
  bf16* xbf = (bf16*)(ws + off);  off += MSZ;
  bf16* w1b = (bf16*)(ws + off);  off += MSZ;
  bf16* w2b = (bf16*)(ws + off);  off += MSZ;
  bf16* w3b = (bf16*)(ws + off);  off += MSZ;
  bf16* w4b = (bf16*)(ws + off);  off += MSZ;
  bf16* hbf = (bf16*)(ws + off);  off += MSZ;
  bf16* qbf  = xbf;   // alias: x dead after GEMM1
  bf16* h2bf = hbf;   // alias: h dead after GEMM2(VQ)

  const int n8 = NB * NF / 8;
  prep_k<<<dim3(4098), dim3(256), 0, stream>>>(x, xbf, W1, w1b, cb, cbbf, cbnorm,
                                               hist, sse, n8);

  dim3 ggrid(256), gblock(512);
  // h = relu(x @ W1^T + b1) -> bf16; background-converts W2
  gemm256<1, 1><<<ggrid, gblock, 0, stream>>>(xbf, w1b, b1, nullptr, hbf,
                                              nullptr, nullptr, nullptr, nullptr,
                                              W2, w2b);
  // latent = h @ W2^T + b2, fused VQ -> qbf + hist + sse; background-converts W3
  gemm256<2, 1><<<ggrid, gblock, 0, stream>>>(hbf, w2b, b2, nullptr, qbf,
                                              cbbf, cbnorm, hist, sse,
                                              W3, w3b);
  // h2 = relu(q @ W3^T + b3) -> bf16; background-converts W4
  gemm256<1, 1><<<ggrid, gblock, 0, stream>>>(qbf, w3b, b3, nullptr, h2bf,
                                              nullptr, nullptr, nullptr, nullptr,
                                              W4, w4b);
  // recons = h2 @ W4^T + b4 -> f32 (d_out)
  gemm256<0, 0><<<ggrid, gblock, 0, stream>>>(h2bf, w4b, b4, out, nullptr,
                                              nullptr, nullptr, nullptr, nullptr,
                                              nullptr, nullptr);

  finalize_k<<<dim3(1), dim3(512), 0, stream>>>(hist, sse, out + (size_t)NB * NF);
}

// Round 18
// 537.651 us; speedup vs baseline: 1.0154x; 1.0045x over previous
//
#include <hip/hip_runtime.h>
#include <stdint.h>
#include <stddef.h>

typedef __bf16 bf16;
typedef __bf16 bf16x8 __attribute__((ext_vector_type(8)));
typedef __bf16 bf16x4 __attribute__((ext_vector_type(4)));
typedef float  f32x4  __attribute__((ext_vector_type(4)));

#define NB      4096        // batch
#define NF      4096        // features (= K = N for all GEMMs)
#define NCODES  (NB * NF / 64)   // 262144
#define NEMB    512
#define EDIM    64

// ---------------------------------------------------------------- helpers
__device__ __forceinline__ void gld_lds16(const void* g, void* l) {
  __builtin_amdgcn_global_load_lds(
      (const __attribute__((address_space(1))) void*)g,
      (__attribute__((address_space(3))) void*)l, 16, 0, 0);
}

__device__ __forceinline__ void cvt8(const float* in, bf16* out, int i) {
  const float4* p = (const float4*)(in + (size_t)i * 8);
  float4 a = p[0], b = p[1];
  bf16x8 o;
  o[0] = (bf16)a.x; o[1] = (bf16)a.y; o[2] = (bf16)a.z; o[3] = (bf16)a.w;
  o[4] = (bf16)b.x; o[5] = (bf16)b.y; o[6] = (bf16)b.z; o[7] = (bf16)b.w;
  *(bf16x8*)(out + (size_t)i * 8) = o;
}

// ---------------------------------------------------------------- prep: cvt(x) + cvt(W1) + cbprep + zero
__global__ void prep_k(const float* __restrict__ x,  bf16* __restrict__ xbf,
                       const float* __restrict__ w1, bf16* __restrict__ w1b,
                       const float* __restrict__ cb, bf16* __restrict__ cbbf,
                       float* __restrict__ cbnorm,
                       unsigned* __restrict__ hist, float* __restrict__ sse, int n8) {
  int b = blockIdx.x, tid = threadIdx.x;
  if (b < 2048) {
    for (int i = b * 256 + tid; i < n8; i += 2048 * 256) cvt8(x, xbf, i);
  } else if (b < 4096) {
    for (int i = (b - 2048) * 256 + tid; i < n8; i += 2048 * 256) cvt8(w1, w1b, i);
  } else {
    int r = (b - 4096) * 256 + tid;
    if (r < NEMB) {
      float s = 0.f;
      for (int d = 0; d < EDIM; ++d) {
        float v = cb[r * EDIM + d];
        s += v * v;
        cbbf[r * EDIM + d] = (bf16)v;
      }
      cbnorm[r] = s;
      hist[r] = 0;
      if (r == 0) sse[0] = 0.f;
    }
  }
}

// ---------------------------------------------------------------- GEMM 256x256, 8-phase/2-tile
// (R7 schedule, frozen; 16x16x32 MFMA). MODE: 0 = f32 out, 1 = bf16 out + relu,
// 2 = fused VQ. DOCVT: background-convert the NEXT gemm's weight using idle HBM BW;
// load after PH4's barrier, store after PH8's barrier (outside counted-vmcnt windows).
// launch_bounds(512,1): LDS (130.5 KB) already caps occupancy at 1 block/CU =
// 2 waves/SIMD, which permits 256 VGPR — the old ",2" bound was over-constraining
// the register allocator (pinned at 128) for zero occupancy benefit.
#define BAR()   __builtin_amdgcn_s_barrier()
#define LGKM(n) asm volatile("s_waitcnt lgkmcnt(" #n ")" ::: "memory")
#define VMC(n)  asm volatile("s_waitcnt vmcnt(" #n ")" ::: "memory")
#define PRIO(n) __builtin_amdgcn_s_setprio(n)

#define RD_A4(d0, d1, base, rb) do {                                          \
    d0[0] = *(const bf16x8*)((base) + (rb)*4096 + 0*1024 + boff0);            \
    d1[0] = *(const bf16x8*)((base) + (rb)*4096 + 0*1024 + boff1);            \
    d0[1] = *(const bf16x8*)((base) + (rb)*4096 + 1*1024 + boff0);            \
    d1[1] = *(const bf16x8*)((base) + (rb)*4096 + 1*1024 + boff1);            \
    d0[2] = *(const bf16x8*)((base) + (rb)*4096 + 2*1024 + boff0);            \
    d1[2] = *(const bf16x8*)((base) + (rb)*4096 + 2*1024 + boff1);            \
    d0[3] = *(const bf16x8*)((base) + (rb)*4096 + 3*1024 + boff0);            \
    d1[3] = *(const bf16x8*)((base) + (rb)*4096 + 3*1024 + boff1); } while (0)

#define RD_B2(d0, d1, base, j0) do {                                          \
    d0[j0]   = *(const bf16x8*)((base) + (j0)*1024     + boff0);              \
    d1[j0]   = *(const bf16x8*)((base) + (j0)*1024     + boff1);              \
    d0[j0+1] = *(const bf16x8*)((base) + ((j0)+1)*1024 + boff0);              \
    d1[j0+1] = *(const bf16x8*)((base) + ((j0)+1)*1024 + boff1); } while (0)

#define MQ(ib, jb, A0a, A1a) do {                                             \
    _Pragma("unroll")                                                         \
    for (int fr = 0; fr < 4; ++fr) {                                          \
      _Pragma("unroll")                                                       \
      for (int jc = 0; jc < 2; ++jc) {                                        \
        acc[(ib)+fr][(jb)+jc] = __builtin_amdgcn_mfma_f32_16x16x32_bf16(      \
            A0a[fr], b0[(jb)+jc], acc[(ib)+fr][(jb)+jc], 0, 0, 0);            \
        acc[(ib)+fr][(jb)+jc] = __builtin_amdgcn_mfma_f32_16x16x32_bf16(      \
            A1a[fr], b1[(jb)+jc], acc[(ib)+fr][(jb)+jc], 0, 0, 0);            \
      } } } while (0)

template<int MODE, int DOCVT>
__global__ __launch_bounds__(512, 1)
void gemm256(const bf16* __restrict__ A, const bf16* __restrict__ W,
             const float* __restrict__ bias,
             float* __restrict__ outF, bf16* __restrict__ outB,
             const bf16* __restrict__ cbbf, const float* __restrict__ cbnorm,
             unsigned int* __restrict__ hist, float* __restrict__ sse_out,
             const float* __restrict__ cvsrc, bf16* __restrict__ cvdst) {
  constexpr int K = 4096, N = 4096, NT = 64;
  __shared__ bf16 SM[65536];          // 128 KB
  __shared__ unsigned lhist[NEMB];    // VQ epilogue only
  __shared__ float swse[8];

  const int tid = threadIdx.x;
  const int wave = tid >> 6, lane = tid & 63;
  const int l15 = lane & 15, lg = lane >> 4;
  const int wm = wave >> 2, wn = wave & 3;
  const int rb0 = (wn & 1) * 64;

  // XCD-bijective swizzle (256 blocks, 256 % 8 == 0)
  const int bid = blockIdx.x;
  const int lb  = (bid & 7) * 32 + (bid >> 3);
  const int bx = lb & 15, by = lb >> 4;
  const int brow = by * 256, bcol = bx * 256;

  // hoisted per-lane ds_read bases
  const int boff0 = l15 * 64 + ((lg ^ (l15 & 7)) * 8);
  const int boff1 = boff0 ^ 32;

  // staging: thread covers units u1,u2 of each 1024-unit half-tile
  const int u1 = tid,       r1 = u1 >> 3, ss1 = (u1 & 7) ^ (r1 & 7);
  const int u2 = tid + 512, r2 = u2 >> 3, ss2 = (u2 & 7) ^ (r2 & 7);
  const size_t tofs1 = (size_t)r1 * K + ss1 * 8;
  const size_t tofs2 = (size_t)r2 * K + ss2 * 8;
  const bf16* gW0 = W + (size_t)bcol * K;
  const bf16* gW1 = W + (size_t)(bcol + 128) * K;
  const bf16* gA0 = A + (size_t)brow * K;
  const bf16* gA1 = A + (size_t)(brow + 128) * K;

  // background-convert slice: block covers 65536 floats, thread 4/iter x 32 iters
  const size_t cvofs = (size_t)bid * 65536 + tid * 4;

#define STAGE(gptr, k_, ldsh) do {                                        \
    gld_lds16((gptr) + tofs1 + (size_t)(k_) * 64, (ldsh) + u1 * 8);       \
    gld_lds16((gptr) + tofs2 + (size_t)(k_) * 64, (ldsh) + u2 * 8); } while (0)

  bf16* as00 = SM;         bf16* as01 = SM + 8192;
  bf16* as10 = SM + 16384; bf16* as11 = SM + 24576;
  bf16* bs00 = SM + 32768; bf16* bs01 = SM + 40960;
  bf16* bs10 = SM + 49152; bf16* bs11 = SM + 57344;

  const bf16* Ae = SM + wm * 8192;
  const bf16* Ao = SM + 16384 + wm * 8192;
  const bf16* Be = SM + 32768 + (wn >> 1) * 8192 + rb0 * 64;
  const bf16* Bo = SM + 49152 + (wn >> 1) * 8192 + rb0 * 64;

  f32x4 acc[8][4];
#pragma unroll
  for (int i = 0; i < 8; ++i)
#pragma unroll
    for (int j = 0; j < 4; ++j)
      acc[i][j] = f32x4{0.f, 0.f, 0.f, 0.f};

  bf16x8 aE0[4], aE1[4];
  bf16x8 aF0[4], aF1[4];
  bf16x8 b0[4],  b1[4];

  // prologue: tile0 complete + tile1 {A0,A1,B0}; vmcnt(6) -> tile0 certified
  STAGE(gA0, 0, as00); STAGE(gA1, 0, as01);
  STAGE(gW0, 0, bs00); STAGE(gW1, 0, bs01);
  STAGE(gA0, 1, as10); STAGE(gA1, 1, as11);
  STAGE(gW0, 1, bs10);
  VMC(6);
  BAR();

  for (int kt = 0; kt < NT; kt += 2) {
    const int kE = (kt + 2) & (NT - 1);
    const int kO = (kt + 3) & (NT - 1);
    float4 cf;

    // PH1
    RD_A4(aE0, aE1, Ae, 0);
    RD_B2(b0, b1, Be, 0);
    STAGE(gW1, kt + 1, bs11);
    LGKM(8); BAR(); LGKM(0);
    PRIO(1); MQ(0, 0, aE0, aE1); PRIO(0); BAR();

    // PH2
    RD_A4(aF0, aF1, Ae, 1);
    STAGE(gA0, kE, as00);
    BAR(); LGKM(0);
    PRIO(1); MQ(4, 0, aF0, aF1); PRIO(0); BAR();

    // PH3
    RD_B2(b0, b1, Be, 2);
    STAGE(gA1, kE, as01);
    BAR(); LGKM(0);
    PRIO(1); MQ(0, 2, aE0, aE1); PRIO(0); BAR();

    // PH4
    STAGE(gW0, kE, bs00);
    BAR();
    PRIO(1); MQ(4, 2, aF0, aF1); PRIO(0);
    VMC(6); BAR();
    if (DOCVT) cf = *(const float4*)(cvsrc + cvofs + (size_t)(kt >> 1) * 2048);

    // PH5
    RD_A4(aE0, aE1, Ao, 0);
    RD_B2(b0, b1, Bo, 0);
    STAGE(gW1, kE, bs01);
    LGKM(8); BAR(); LGKM(0);
    PRIO(1); MQ(0, 0, aE0, aE1); PRIO(0); BAR();

    // PH6
    RD_A4(aF0, aF1, Ao, 1);
    STAGE(gA0, kO, as10);
    BAR(); LGKM(0);
    PRIO(1); MQ(4, 0, aF0, aF1); PRIO(0); BAR();

    // PH7
    RD_B2(b0, b1, Bo, 2);
    STAGE(gA1, kO, as11);
    BAR(); LGKM(0);
    PRIO(1); MQ(0, 2, aE0, aE1); PRIO(0); BAR();

    // PH8
    STAGE(gW0, kO, bs10);
    BAR();
    PRIO(1); MQ(4, 2, aF0, aF1); PRIO(0);
    VMC(6); BAR();
    if (DOCVT) {
      bf16x4 c4;
      c4[0] = (bf16)cf.x; c4[1] = (bf16)cf.y; c4[2] = (bf16)cf.z; c4[3] = (bf16)cf.w;
      *(bf16x4*)(cvdst + cvofs + (size_t)(kt >> 1) * 2048) = c4;
    }
  }
#undef STAGE

  if (MODE == 2) {
    // -------- fused VQ epilogue (single-pass; bf16 codebook for qv/SSE) --------
    __syncthreads();                 // all LDS reads of the K-loop done
    lhist[tid] = 0;
    // write (acc + bias) as bf16 codes into wave-private swizzled scratch
    bf16* scr = SM + wave * 8192;    // 128 rows x 64 dims, main-loop swizzle geometry
#pragma unroll
    for (int j = 0; j < 4; ++j) {
      float bv = bias[bcol + wn * 64 + j * 16 + l15];
#pragma unroll
      for (int i = 0; i < 8; ++i) {
#pragma unroll
        for (int rr = 0; rr < 4; ++rr) {
          int r = i * 16 + lg * 4 + rr;
          int d = j * 16 + l15;
          scr[r * 64 + (((d >> 3) ^ (r & 7)) << 3) + (d & 7)] =
              (bf16)(acc[i][j][rr] + bv);
        }
      }
    }
    __syncthreads();

    // load all 8 code-groups as A-frags
    bf16x8 ca0[8], ca1[8];
#pragma unroll
    for (int g = 0; g < 8; ++g) {
      ca0[g] = *(const bf16x8*)(scr + g * 1024 + boff0);
      ca1[g] = *(const bf16x8*)(scr + g * 1024 + boff1);
    }
    float best[8][4];
    int   bidx[8][4];
#pragma unroll
    for (int g = 0; g < 8; ++g)
#pragma unroll
      for (int r = 0; r < 4; ++r) { best[g][r] = 1e30f; bidx[g][r] = 0; }

#pragma unroll 4
    for (int ct = 0; ct < 32; ++ct) {
      const bf16* bp = cbbf + (ct * 16 + l15) * 64 + lg * 8;
      bf16x8 q0 = *(const bf16x8*)bp;
      bf16x8 q1 = *(const bf16x8*)(bp + 32);
      float cn = cbnorm[ct * 16 + l15];
      int c = ct * 16 + l15;
#pragma unroll
      for (int g = 0; g < 8; ++g) {
        f32x4 da = f32x4{0.f, 0.f, 0.f, 0.f};
        da = __builtin_amdgcn_mfma_f32_16x16x32_bf16(ca0[g], q0, da, 0, 0, 0);
        da = __builtin_amdgcn_mfma_f32_16x16x32_bf16(ca1[g], q1, da, 0, 0, 0);
#pragma unroll
        for (int r = 0; r < 4; ++r) {
          float s = fmaf(-2.0f, da[r], cn);
          if (s < best[g][r]) { best[g][r] = s; bidx[g][r] = c; }
        }
      }
    }

    float sse = 0.f;
    const int gcol = bcol + wn * 64;
#pragma unroll
    for (int g = 0; g < 8; ++g) {
#pragma unroll
      for (int r = 0; r < 4; ++r) {
        uint32_t bits = __float_as_uint(best[g][r]);
        uint32_t u = bits ^ ((uint32_t)((int32_t)bits >> 31) | 0x80000000u);
        uint32_t key = (u & 0xFFFFFE00u) | (uint32_t)bidx[g][r];
#pragma unroll
        for (int m = 1; m < 16; m <<= 1) {
          uint32_t o = __shfl_xor(key, m);
          key = (o < key) ? o : key;
        }
        int idx = (int)(key & 511u);
        int rowl = g * 16 + lg * 4 + r;
        bf16x4 cv = *(const bf16x4*)(scr + rowl * 64 +
                        (((l15 >> 1) ^ (rowl & 7)) << 3) + (l15 & 1) * 4);
        // quantized entry direct from bf16 codebook: identical bits to (bf16)cb
        bf16x4 ev = *(const bf16x4*)(cbbf + (size_t)idx * EDIM + l15 * 4);
        float d0 = (float)ev[0] - (float)cv[0], d1 = (float)ev[1] - (float)cv[1];
        float d2 = (float)ev[2] - (float)cv[2], d3 = (float)ev[3] - (float)cv[3];
        sse += d0 * d0 + d1 * d1 + d2 * d2 + d3 * d3;
        *(bf16x4*)(outB + (size_t)(brow + wm * 128 + rowl) * N + gcol + l15 * 4) = ev;
        if (l15 == 0) atomicAdd(&lhist[idx], 1u);
      }
    }
#pragma unroll
    for (int m = 1; m < 64; m <<= 1) sse += __shfl_xor(sse, m);
    if (lane == 0) swse[wave] = sse;
    __syncthreads();
    { unsigned v = lhist[tid]; if (v) atomicAdd(hist + tid, v); }
    if (tid == 0) {
      float s = 0.f;
#pragma unroll
      for (int w = 0; w < 8; ++w) s += swse[w];
      atomicAdd(sse_out, s);
    }
    return;
  }

  // -------- dense epilogue (MODE 0/1) --------
#pragma unroll
  for (int j = 0; j < 4; ++j) {
    int col = bcol + wn * 64 + j * 16 + l15;
    float bv = bias[col];
#pragma unroll
    for (int i = 0; i < 8; ++i) {
#pragma unroll
      for (int rr = 0; rr < 4; ++rr) {
        int row = brow + wm * 128 + i * 16 + lg * 4 + rr;
        float v = acc[i][j][rr] + bv;
        if (MODE == 1) v = fmaxf(v, 0.f);
        size_t o = (size_t)row * N + col;
        if (MODE == 0) outF[o] = v;
        else           outB[o] = (bf16)v;
      }
    }
  }
}

// ---------------------------------------------------------------- finalize: vq_loss + perplexity
__global__ void finalize_k(const unsigned* __restrict__ hist, const float* __restrict__ sse,
                           float* __restrict__ out_tail) {
  __shared__ float red[512];
  int t = threadIdx.x;
  float p = (float)hist[t] * (1.0f / (float)NCODES);
  red[t] = p * logf(p + 1e-10f);
  __syncthreads();
  for (int s = 256; s > 0; s >>= 1) {
    if (t < s) red[t] += red[t + s];
    __syncthreads();
  }
  if (t == 0) {
    out_tail[0] = 1.25f * sse[0] * (1.0f / ((float)NCODES * (float)EDIM));
    out_tail[1] = expf(-red[0]);
  }
}

// ---------------------------------------------------------------- launch
extern "C" void kernel_launch(void* const* d_in, const int* in_sizes, int n_in,
                              void* d_out, int out_size, void* d_ws, size_t ws_size,
                              hipStream_t stream) {
  const float* x  = (const float*)d_in[0];
  const float* W1 = (const float*)d_in[1];
  const float* b1 = (const float*)d_in[2];
  const float* W2 = (const float*)d_in[3];
  const float* b2 = (const float*)d_in[4];
  const float* W3 = (const float*)d_in[5];
  const float* b3 = (const float*)d_in[6];
  const float* W4 = (const float*)d_in[7];
  const float* b4 = (const float*)d_in[8];
  const float* cb = (const float*)d_in[9];
  float* out = (float*)d_out;

  char* ws = (char*)d_ws;
  float*    sse    = (float*)(ws + 0);
  unsigned* hist   = (unsigned*)(ws + 1024);
  float*    cbnorm = (float*)(ws + 4096);
  bf16*     cbbf   = (bf16*)(ws + 8192);
  size_t off = 131072;
  const size_t MSZ = (size_t)NB * NF * 2;          // 33.5 MB
  bf16* xbf = (bf16*)(ws + off);  off += MSZ;
  bf16* w1b = (bf16*)(ws + off);  off += MSZ;
  bf16* w2b = (bf16*)(ws + off);  off += MSZ;
  bf16* w3b = (bf16*)(ws + off);  off += MSZ;
  bf16* w4b = (bf16*)(ws + off);  off += MSZ;
  bf16* hbf = (bf16*)(ws + off);  off += MSZ;
  bf16* qbf  = xbf;   // alias: x dead after GEMM1
  bf16* h2bf = hbf;   // alias: h dead after GEMM2(VQ)

  const int n8 = NB * NF / 8;
  prep_k<<<dim3(4098), dim3(256), 0, stream>>>(x, xbf, W1, w1b, cb, cbbf, cbnorm,
                                               hist, sse, n8);

  dim3 ggrid(256), gblock(512);
  // h = relu(x @ W1^T + b1) -> bf16; background-converts W2
  gemm256<1, 1><<<ggrid, gblock, 0, stream>>>(xbf, w1b, b1, nullptr, hbf,
                                              nullptr, nullptr, nullptr, nullptr,
                                              W2, w2b);
  // latent = h @ W2^T + b2, fused VQ -> qbf + hist + sse; background-converts W3
  gemm256<2, 1><<<ggrid, gblock, 0, stream>>>(hbf, w2b, b2, nullptr, qbf,
                                              cbbf, cbnorm, hist, sse,
                                              W3, w3b);
  // h2 = relu(q @ W3^T + b3) -> bf16; background-converts W4
  gemm256<1, 1><<<ggrid, gblock, 0, stream>>>(qbf, w3b, b3, nullptr, h2bf,
                                              nullptr, nullptr, nullptr, nullptr,
                                              W4, w4b);
  // recons = h2 @ W4^T + b4 -> f32 (d_out)
  gemm256<0, 0><<<ggrid, gblock, 0, stream>>>(h2bf, w4b, b4, out, nullptr,
                                              nullptr, nullptr, nullptr, nullptr,
                                              nullptr, nullptr);

  finalize_k<<<dim3(1), dim3(512), 0, stream>>>(hist, sse, out + (size_t)NB * NF);
}